// Round 1
// baseline (169.257 us; speedup 1.0000x reference)
//
#include <hip/hip_runtime.h>
#include <hip/hip_fp16.h>

#define N_NODES 10000
#define N_EDGES 640000
#define N_GRAPHS 64
#define FEATS 128

#define NSLICE 128
#define EPS (N_EDGES / NSLICE)   // 5000 edges per slice
#define CAP 128                  // padded per-node edge capacity (mean deg 64, 128 = +8sigma)
#define PRE_BLOCKS 1250          // 320000 float4 / 256

static inline size_t align_up(size_t x, size_t a) { return (x + a - 1) & ~(a - 1); }

// ---------------------------------------------------------------------------
// 1) HIST: blocks 0..127 histogram dst-slice b; blocks 128..255 histogram
//    src-slice (b-128). 256 blocks -> full GPU (was 128 / half idle).
//    Block 0 also zero-inits graph_cnt/graph_sum.
__global__ __launch_bounds__(256) void hist_kernel(const int* __restrict__ src,
                                                   const int* __restrict__ dst,
                                                   unsigned short* __restrict__ counts,
                                                   unsigned short* __restrict__ scounts,
                                                   int* __restrict__ graph_cnt,
                                                   float* __restrict__ graph_sum) {
    __shared__ int h[N_NODES];
    const int tid = threadIdx.x;
    const int b = blockIdx.x;
    if (b == 0 && tid < 2 * N_GRAPHS) {
        if (tid < N_GRAPHS) graph_cnt[tid] = 0;
        else                graph_sum[tid - N_GRAPHS] = 0.f;
    }
    const bool is_dst = (b < NSLICE);
    const int slice = is_dst ? b : b - NSLICE;
    const int* col = is_dst ? dst : src;
    unsigned short* outp = (is_dst ? counts : scounts) + slice * N_NODES;

    for (int i = tid; i < N_NODES; i += 256) h[i] = 0;
    __syncthreads();
    const int4* c4 = (const int4*)(col + slice * EPS);
    for (int i = tid; i < EPS / 4; i += 256) {
        int4 v = c4[i];
        atomicAdd(&h[v.x], 1);
        atomicAdd(&h[v.y], 1);
        atomicAdd(&h[v.z], 1);
        atomicAdd(&h[v.w], 1);
    }
    __syncthreads();
    for (int i = tid; i < N_NODES; i += 256) outp[i] = (unsigned short)h[i];
}

// ---------------------------------------------------------------------------
// 2) DEGNORM+BASE: per node n, scan ushort counts along 128 slices into int
//    write bases seeded with n*CAP; deg_in / norms / graph counts same pass.
//    64-thread blocks x 157 -> spread over ~157 CUs (was 40 blocks / 40 CUs);
//    the 256 independent loads per thread pipeline fine at 1 wave/CU.
__global__ __launch_bounds__(64) void degnorm_base_kernel(const unsigned short* __restrict__ counts,
                                                          const unsigned short* __restrict__ scounts,
                                                          const int* __restrict__ gids,
                                                          int* __restrict__ bases,
                                                          int* __restrict__ deg_in,
                                                          float* __restrict__ norm_src,
                                                          float* __restrict__ norm_dst,
                                                          int* __restrict__ graph_cnt) {
    __shared__ int gcnt[N_GRAPHS];
    const int tid = threadIdx.x;
    gcnt[tid] = 0;  // 64 threads == N_GRAPHS
    __syncthreads();
    int n = blockIdx.x * 64 + tid;
    if (n < N_NODES) {
        int run = n * CAP;
        for (int s = 0; s < NSLICE; s++) {
            int c = counts[s * N_NODES + n];
            bases[s * N_NODES + n] = run;
            run += c;
        }
        int di = run - n * CAP;
        int dou = 0;
        for (int s = 0; s < NSLICE; s++) dou += scounts[s * N_NODES + n];
        deg_in[n] = di;
        norm_dst[n] = rsqrtf((float)(di < 1 ? 1 : di));
        norm_src[n] = rsqrtf((float)(dou < 1 ? 1 : dou));
        atomicAdd(&gcnt[gids[n]], 1);
    }
    __syncthreads();
    if (gcnt[tid]) atomicAdd(&graph_cnt[tid], gcnt[tid]);
}

// ---------------------------------------------------------------------------
// 3) SCATTER+PRESCALE (independent work, one dispatch):
//    blocks 0..127: place EPS edges via LDS cursors into the padded CSR
//    (2x the random-write parallelism of the 64-slice version);
//    blocks 128..1377: xs = fp16(in_feat * norm_src) at full streaming width.
__global__ __launch_bounds__(256) void scatter_prescale_kernel(const int* __restrict__ src,
                                                               const int* __restrict__ dst,
                                                               const int* __restrict__ bases,
                                                               int* __restrict__ sorted_src,
                                                               const float* __restrict__ in_feat,
                                                               const float* __restrict__ norm_src,
                                                               __half* __restrict__ xs) {
    const int tid = threadIdx.x;
    if (blockIdx.x < NSLICE) {
        __shared__ int cur[N_NODES];
        const int s = blockIdx.x;
        for (int i = tid; i < N_NODES; i += 256) cur[i] = bases[s * N_NODES + i];
        __syncthreads();
        const int4* s4 = (const int4*)(src + s * EPS);
        const int4* d4 = (const int4*)(dst + s * EPS);
        for (int i = tid; i < EPS / 4; i += 256) {
            int4 sv = s4[i];
            int4 dv = d4[i];
            int p;
            p = atomicAdd(&cur[dv.x], 1); sorted_src[p] = sv.x;
            p = atomicAdd(&cur[dv.y], 1); sorted_src[p] = sv.y;
            p = atomicAdd(&cur[dv.z], 1); sorted_src[p] = sv.z;
            p = atomicAdd(&cur[dv.w], 1); sorted_src[p] = sv.w;
        }
    } else {
        int i = (blockIdx.x - NSLICE) * 256 + tid;  // over 320000 float4
        if (i < N_NODES * (FEATS / 4)) {
            int n = i >> 5;
            float4 v = ((const float4*)in_feat)[i];
            float s = norm_src[n];
            __half2 h0 = __floats2half2_rn(v.x * s, v.y * s);
            __half2 h1 = __floats2half2_rn(v.z * s, v.w * s);
            __half2* o = (__half2*)(xs + (size_t)i * 4);
            o[0] = h0; o[1] = h1;
        }
    }
}

// ---------------------------------------------------------------------------
// Per-wave aggregation of one dst node into an LDS fp32 row (norm_dst applied).
// Quarter-wave (16 lanes x 16 B) fetches one 256 B fp16 row per instr ->
// 4 edges per wave instruction; unroll x4 keeps 16 rows in flight per wave.
__device__ __forceinline__ void wave_aggregate(const __half* __restrict__ X,
                                               const int* __restrict__ sorted_src,
                                               const int* __restrict__ deg_in,
                                               const float* __restrict__ norm_dst,
                                               int n, int lane,
                                               float* __restrict__ As_row) {
    const int grp = lane >> 4, l16 = lane & 15;
    const int start = n * CAP;
    const int cnt = deg_in[n];
    const uint4* __restrict__ x4 = (const uint4*)X;  // row = 16 uint4 (256 B)
    float acc[8] = {0.f, 0.f, 0.f, 0.f, 0.f, 0.f, 0.f, 0.f};

    // group `grp` handles edges congruent to `grp` (mod 4)
    int c = grp;
    for (; c + 12 < cnt; c += 16) {
        int idx[4];
#pragma unroll
        for (int k = 0; k < 4; k++) idx[k] = sorted_src[start + c + 4 * k];
        uint4 v[4];
#pragma unroll
        for (int k = 0; k < 4; k++) v[k] = x4[idx[k] * 16 + l16];
#pragma unroll
        for (int k = 0; k < 4; k++) {
            const __half2* hp = (const __half2*)&v[k];
#pragma unroll
            for (int j = 0; j < 4; j++) {
                float2 f = __half22float2(hp[j]);
                acc[2 * j]     += f.x;
                acc[2 * j + 1] += f.y;
            }
        }
    }
    for (; c < cnt; c += 4) {
        uint4 v = x4[sorted_src[start + c] * 16 + l16];
        const __half2* hp = (const __half2*)&v;
#pragma unroll
        for (int j = 0; j < 4; j++) {
            float2 f = __half22float2(hp[j]);
            acc[2 * j]     += f.x;
            acc[2 * j + 1] += f.y;
        }
    }
    // combine the 4 groups (same feature columns in all groups)
#pragma unroll
    for (int j = 0; j < 8; j++) {
        acc[j] += __shfl_xor(acc[j], 16);
        acc[j] += __shfl_xor(acc[j], 32);
    }
    if (grp == 0) {
        const float nd = norm_dst[n];
        float4 f0 = make_float4(acc[0] * nd, acc[1] * nd, acc[2] * nd, acc[3] * nd);
        float4 f1 = make_float4(acc[4] * nd, acc[5] * nd, acc[6] * nd, acc[7] * nd);
        *(float4*)(As_row + l16 * 8)     = f0;
        *(float4*)(As_row + l16 * 8 + 4) = f1;
    }
}

// ---------------------------------------------------------------------------
// 4) FUSED LAYER 1: per block of 16 nodes, aggregate xs into LDS (fp32,
//    norm_dst applied), then h = fp16(norm_src * relu(As @ W1 + b1)).
//    Removes the agg1 fp16 round trip + one dispatch; A stays fp32.
__global__ __launch_bounds__(256) void fused_layer1_kernel(const __half* __restrict__ xs,
                                                           const int* __restrict__ sorted_src,
                                                           const int* __restrict__ deg_in,
                                                           const float* __restrict__ norm_dst,
                                                           const float* __restrict__ W,
                                                           const float* __restrict__ bias,
                                                           const float* __restrict__ scale,
                                                           __half* __restrict__ out) {
    __shared__ float As[16 * FEATS];
    const int tid = threadIdx.x;
    const int nb = blockIdx.x * 16;
    const int wave = tid >> 6, lane = tid & 63;
#pragma unroll
    for (int i = 0; i < 4; i++) {
        int ln = wave * 4 + i;
        wave_aggregate(xs, sorted_src, deg_in, norm_dst, nb + ln, lane, As + ln * FEATS);
    }
    __syncthreads();
    int fg = (tid & 31) << 2;
    int r  = tid >> 5;
    const float* a0p = As + r * FEATS;
    const float* a1p = As + (r + 8) * FEATS;
    float4 acc0 = make_float4(0.f, 0.f, 0.f, 0.f);
    float4 acc1 = make_float4(0.f, 0.f, 0.f, 0.f);
#pragma unroll 4
    for (int k = 0; k < FEATS; k++) {
        float a0 = a0p[k];
        float a1 = a1p[k];
        float4 w = *(const float4*)(W + k * FEATS + fg);
        acc0.x = fmaf(a0, w.x, acc0.x); acc0.y = fmaf(a0, w.y, acc0.y);
        acc0.z = fmaf(a0, w.z, acc0.z); acc0.w = fmaf(a0, w.w, acc0.w);
        acc1.x = fmaf(a1, w.x, acc1.x); acc1.y = fmaf(a1, w.y, acc1.y);
        acc1.z = fmaf(a1, w.z, acc1.z); acc1.w = fmaf(a1, w.w, acc1.w);
    }
    float4 bb = *(const float4*)(bias + fg);
    int gn0 = nb + r, gn1 = nb + r + 8;
    float s0 = scale[gn0], s1 = scale[gn1];
    __half2 h00 = __floats2half2_rn(fmaxf(acc0.x + bb.x, 0.f) * s0,
                                    fmaxf(acc0.y + bb.y, 0.f) * s0);
    __half2 h01 = __floats2half2_rn(fmaxf(acc0.z + bb.z, 0.f) * s0,
                                    fmaxf(acc0.w + bb.w, 0.f) * s0);
    __half2 h10 = __floats2half2_rn(fmaxf(acc1.x + bb.x, 0.f) * s1,
                                    fmaxf(acc1.y + bb.y, 0.f) * s1);
    __half2 h11 = __floats2half2_rn(fmaxf(acc1.z + bb.z, 0.f) * s1,
                                    fmaxf(acc1.w + bb.w, 0.f) * s1);
    __half2* o0 = (__half2*)(out + (size_t)gn0 * FEATS + fg);
    __half2* o1 = (__half2*)(out + (size_t)gn1 * FEATS + fg);
    o0[0] = h00; o0[1] = h01;
    o1[0] = h10; o1[1] = h11;
}

// ---------------------------------------------------------------------------
// 5) FUSED LAYER 2 + POOL: aggregate h into LDS, then per node
//    s = relu(As@W2+b2) . Wd ; LDS 64-bin accumulate, few global atomics
//    per block (gids sorted -> 1-2 bins/block). No device-scope fence.
__global__ __launch_bounds__(256) void fused_layer2_kernel(const __half* __restrict__ h,
                                                           const int* __restrict__ sorted_src,
                                                           const int* __restrict__ deg_in,
                                                           const float* __restrict__ norm_dst,
                                                           const float* __restrict__ W,
                                                           const float* __restrict__ bias,
                                                           const float* __restrict__ Wd,
                                                           const int* __restrict__ gids,
                                                           float* __restrict__ graph_sum) {
    __shared__ float As[16 * FEATS];
    __shared__ float bins[N_GRAPHS];
    const int tid = threadIdx.x;
    const int nb = blockIdx.x * 16;
    const int wave = tid >> 6, lane = tid & 63;
    if (tid < N_GRAPHS) bins[tid] = 0.f;
#pragma unroll
    for (int i = 0; i < 4; i++) {
        int ln = wave * 4 + i;
        wave_aggregate(h, sorted_src, deg_in, norm_dst, nb + ln, lane, As + ln * FEATS);
    }
    __syncthreads();
    int fg = (tid & 31) << 2;
    int r  = tid >> 5;
    const float* a0p = As + r * FEATS;
    const float* a1p = As + (r + 8) * FEATS;
    float4 acc0 = make_float4(0.f, 0.f, 0.f, 0.f);
    float4 acc1 = make_float4(0.f, 0.f, 0.f, 0.f);
#pragma unroll 4
    for (int k = 0; k < FEATS; k++) {
        float a0 = a0p[k];
        float a1 = a1p[k];
        float4 w = *(const float4*)(W + k * FEATS + fg);
        acc0.x = fmaf(a0, w.x, acc0.x); acc0.y = fmaf(a0, w.y, acc0.y);
        acc0.z = fmaf(a0, w.z, acc0.z); acc0.w = fmaf(a0, w.w, acc0.w);
        acc1.x = fmaf(a1, w.x, acc1.x); acc1.y = fmaf(a1, w.y, acc1.y);
        acc1.z = fmaf(a1, w.z, acc1.z); acc1.w = fmaf(a1, w.w, acc1.w);
    }
    float4 bb = *(const float4*)(bias + fg);
    float4 wd = *(const float4*)(Wd + fg);
    float p0 = fmaxf(acc0.x + bb.x, 0.f) * wd.x + fmaxf(acc0.y + bb.y, 0.f) * wd.y +
               fmaxf(acc0.z + bb.z, 0.f) * wd.z + fmaxf(acc0.w + bb.w, 0.f) * wd.w;
    float p1 = fmaxf(acc1.x + bb.x, 0.f) * wd.x + fmaxf(acc1.y + bb.y, 0.f) * wd.y +
               fmaxf(acc1.z + bb.z, 0.f) * wd.z + fmaxf(acc1.w + bb.w, 0.f) * wd.w;
#pragma unroll
    for (int d = 16; d >= 1; d >>= 1) {
        p0 += __shfl_down(p0, d);
        p1 += __shfl_down(p1, d);
    }
    if ((tid & 31) == 0) {
        int gn0 = nb + r, gn1 = nb + r + 8;
        atomicAdd(&bins[gids[gn0]], p0);
        atomicAdd(&bins[gids[gn1]], p1);
    }
    __syncthreads();
    if (tid < N_GRAPHS) {
        float v = bins[tid];
        if (v != 0.f) atomicAdd(&graph_sum[tid], v);
    }
}

// ---------------------------------------------------------------------------
// 6) final: out[g] = graph_sum[g] / max(cnt,1) + bd
__global__ __launch_bounds__(64) void final_kernel(const float* __restrict__ graph_sum,
                                                   const int* __restrict__ graph_cnt,
                                                   const float* __restrict__ bd,
                                                   float* __restrict__ out) {
    int g = threadIdx.x;
    if (g < N_GRAPHS) {
        out[g] = graph_sum[g] / fmaxf((float)graph_cnt[g], 1.f) + bd[0];
    }
}

// ---------------------------------------------------------------------------
extern "C" void kernel_launch(void* const* d_in, const int* in_sizes, int n_in,
                              void* d_out, int out_size, void* d_ws, size_t ws_size,
                              hipStream_t stream) {
    const float* in_feat = (const float*)d_in[0];
    const int*   src     = (const int*)d_in[1];
    const int*   dst     = (const int*)d_in[2];
    const int*   gids    = (const int*)d_in[3];
    const float* W1      = (const float*)d_in[4];
    const float* b1      = (const float*)d_in[5];
    const float* W2      = (const float*)d_in[6];
    const float* b2      = (const float*)d_in[7];
    const float* Wd      = (const float*)d_in[8];
    const float* bd      = (const float*)d_in[9];
    float* out = (float*)d_out;

    char* ws = (char*)d_ws;
    size_t off = 0;
    int* graph_cnt = (int*)(ws + off); off += N_GRAPHS * 4;
    float* graph_sum = (float*)(ws + off); off += N_GRAPHS * 4;
    off = align_up(off, 512);
    unsigned short* counts  = (unsigned short*)(ws + off); off += (size_t)NSLICE * N_NODES * 2; // 2.56 MB
    off = align_up(off, 512);
    unsigned short* scounts = (unsigned short*)(ws + off); off += (size_t)NSLICE * N_NODES * 2; // 2.56 MB
    off = align_up(off, 512);
    int* bases = (int*)(ws + off); off += (size_t)NSLICE * N_NODES * 4;     // 5.12 MB
    off = align_up(off, 512);
    int* deg_in  = (int*)(ws + off); off += N_NODES * 4;
    off = align_up(off, 512);
    float* norm_src = (float*)(ws + off); off += N_NODES * 4;
    off = align_up(off, 512);
    float* norm_dst = (float*)(ws + off); off += N_NODES * 4;
    off = align_up(off, 512);
    int* sorted_src = (int*)(ws + off); off += (size_t)N_NODES * CAP * 4 + 4096;  // 5.12 MB
    off = align_up(off, 512);
    __half* xs   = (__half*)(ws + off); off += (size_t)N_NODES * FEATS * 2; // 2.56 MB
    off = align_up(off, 512);
    __half* h    = (__half*)(ws + off); off += (size_t)N_NODES * FEATS * 2; // 2.56 MB
    (void)ws_size; // ~20.6 MB used

    hist_kernel<<<2 * NSLICE, 256, 0, stream>>>(src, dst, counts, scounts,
                                                graph_cnt, graph_sum);
    degnorm_base_kernel<<<(N_NODES + 63) / 64, 64, 0, stream>>>(counts, scounts, gids,
                                                                bases, deg_in, norm_src,
                                                                norm_dst, graph_cnt);
    scatter_prescale_kernel<<<NSLICE + PRE_BLOCKS, 256, 0, stream>>>(src, dst, bases,
                                                                     sorted_src, in_feat,
                                                                     norm_src, xs);

    // layer 1 (fused aggregate + gemm; h written pre-scaled by norm_src, fp16)
    fused_layer1_kernel<<<N_NODES / 16, 256, 0, stream>>>(xs, sorted_src, deg_in, norm_dst,
                                                          W1, b1, norm_src, h);
    // layer 2 (fused aggregate + gemm + pool)
    fused_layer2_kernel<<<N_NODES / 16, 256, 0, stream>>>(h, sorted_src, deg_in, norm_dst,
                                                          W2, b2, Wd, gids, graph_sum);

    final_kernel<<<1, 64, 0, stream>>>(graph_sum, graph_cnt, bd, out);
}